// Round 3
// baseline (404.772 us; speedup 1.0000x reference)
//
#include <hip/hip_runtime.h>
#include <math.h>

// AvU loss over [N, 32] f32 logits.
// 8 lanes/row: each wave global_load_dwordx4 reads 1 KiB contiguous.
// 4-deep software pipeline (4 outstanding 1 KiB loads/wave) + nontemporal
// loads; EXACT template path removes all per-iteration bounds branches.
// Per-block partials in d_ws, tiny final-reduce kernel.

typedef float f32x4 __attribute__((ext_vector_type(4)));

template<bool EXACT>
__global__ __launch_bounds__(256) void avu_main(
    const float* __restrict__ logits,
    const int* __restrict__ labels,
    const float* __restrict__ unc_th_p,
    float4* __restrict__ partials,   // [gridDim.x]
    int N)
{
    const float unc_th = unc_th_p[0];
    const f32x4* __restrict__ p4 = (const f32x4*)logits;

    const int lane = threadIdx.x & 63;
    const int wave = threadIdx.x >> 6;
    const int sub  = lane & 7;    // which float4 within the row
    const int rgrp = lane >> 3;   // which row within the 8-row group

    const int wavesPerBlock = blockDim.x >> 6;
    const int W  = blockIdx.x * wavesPerBlock + wave;   // global wave id
    const int TW = gridDim.x * wavesPerBlock;           // total waves

    const int G   = (N + 7) >> 3;          // number of 8-row groups
    const int gpw = EXACT ? (G / TW) : ((G + TW - 1) / TW);
    const int g0  = W * gpw;

    float acc0 = 0.f, acc1 = 0.f, acc2 = 0.f, acc3 = 0.f;

    // 4-deep prefetch: slots j hold groups g0+j
    f32x4 v[4];
    int   lab[4];
#pragma unroll
    for (int j = 0; j < 4; ++j) {
        const int g = g0 + j;
        if (EXACT || (g < G && j < gpw)) {
            v[j]   = __builtin_nontemporal_load(&p4[(size_t)g * 64 + lane]);
            const int row = (g << 3) + rgrp;
            lab[j] = (EXACT || row < N) ? labels[row] : -1;
        } else {
            v[j] = (f32x4){0.f, 0.f, 0.f, 0.f};
            lab[j] = -1;
        }
    }

    for (int i = 0; i < gpw; ++i) {
        const int g = g0 + i;
        if (!EXACT && g >= G) break;

        const int j = i & 3;
        const f32x4 cv  = v[j];
        const int   clab = lab[j];

        // refill slot j with group g+4
        const int gn = g + 4;
        if ((i + 4 < gpw) && (EXACT || gn < G)) {
            v[j] = __builtin_nontemporal_load(&p4[(size_t)gn * 64 + lane]);
            const int rown = (gn << 3) + rgrp;
            lab[j] = (EXACT || rown < N) ? labels[rown] : -1;
        }

        const int row   = (g << 3) + rgrp;
        const bool valid = EXACT || (row < N);

        // per-lane max/argmax over 4 elements (first-occurrence ties)
        const int base = sub << 2;
        float m = cv.x; int mi = base;
        if (cv.y > m) { m = cv.y; mi = base + 1; }
        if (cv.z > m) { m = cv.z; mi = base + 2; }
        if (cv.w > m) { m = cv.w; mi = base + 3; }

        // 8-lane butterfly argmax (tie -> smaller index)
#pragma unroll
        for (int mask = 1; mask <= 4; mask <<= 1) {
            const float om = __shfl_xor(m, mask);
            const int   oi = __shfl_xor(mi, mask);
            if (om > m || (om == m && oi < mi)) { m = om; mi = oi; }
        }

        // S = sum exp(x-m); dot = sum exp(x-m)*(x-m)
        const float d0 = cv.x - m, d1 = cv.y - m, d2 = cv.z - m, d3 = cv.w - m;
        const float e0 = __expf(d0), e1 = __expf(d1);
        const float e2 = __expf(d2), e3 = __expf(d3);
        float S   = (e0 + e1) + (e2 + e3);
        float dot = (e0 * d0 + e1 * d1) + (e2 * d2 + e3 * d3);
#pragma unroll
        for (int mask = 1; mask <= 4; mask <<= 1) {
            S   += __shfl_xor(S, mask);
            dot += __shfl_xor(dot, mask);
        }

        const float rS   = 1.0f / S;
        const float conf = rS;                     // max prob = exp(0)/S
        const float unc  = __logf(S) - dot * rS;   // entropy, in [0, log 32]
        // tanh(u) = 1 - 2/(e^{2u}+1), u >= 0 so no overflow
        const float t = 1.0f - 2.0f / (__expf(2.0f * unc) + 1.0f);

        const bool accurate = (clab == mi);
        const bool certain  = (unc <= unc_th);

        const float a = accurate ? conf : (1.0f - conf);
        const float w = certain ? (1.0f - t) : t;
        float val = a * w;
        val = (sub == 0 && valid) ? val : 0.f;     // one contribution per row

        acc0 += ( accurate &&  certain) ? val : 0.f;  // n_ac
        acc1 += ( accurate && !certain) ? val : 0.f;  // n_au
        acc2 += (!accurate &&  certain) ? val : 0.f;  // n_ic
        acc3 += (!accurate && !certain) ? val : 0.f;  // n_iu
    }

    // full-wave butterfly reduction
#pragma unroll
    for (int mask = 1; mask <= 32; mask <<= 1) {
        acc0 += __shfl_xor(acc0, mask);
        acc1 += __shfl_xor(acc1, mask);
        acc2 += __shfl_xor(acc2, mask);
        acc3 += __shfl_xor(acc3, mask);
    }

    __shared__ float4 red[4];
    if (lane == 0) red[wave] = make_float4(acc0, acc1, acc2, acc3);
    __syncthreads();

    if (threadIdx.x == 0) {
        float4 r = red[0];
        for (int w2 = 1; w2 < wavesPerBlock; ++w2) {
            const float4 q = red[w2];
            r.x += q.x; r.y += q.y; r.z += q.z; r.w += q.w;
        }
        partials[blockIdx.x] = r;
    }
}

__global__ __launch_bounds__(64) void avu_final(
    const float4* __restrict__ partials, int nPart,
    float* __restrict__ out)
{
    double s0 = 0.0, s1 = 0.0, s2 = 0.0, s3 = 0.0;
    for (int i = threadIdx.x; i < nPart; i += 64) {
        const float4 p = partials[i];
        s0 += (double)p.x; s1 += (double)p.y;
        s2 += (double)p.z; s3 += (double)p.w;
    }
#pragma unroll
    for (int mask = 1; mask <= 32; mask <<= 1) {
        s0 += __shfl_xor(s0, mask);
        s1 += __shfl_xor(s1, mask);
        s2 += __shfl_xor(s2, mask);
        s3 += __shfl_xor(s3, mask);
    }
    if (threadIdx.x == 0) {
        const double avu = (s0 + s3) / (s0 + s1 + s2 + s3 + 1e-10);
        out[0] = (float)(-log(avu + 1e-10));
    }
}

extern "C" void kernel_launch(void* const* d_in, const int* in_sizes, int n_in,
                              void* d_out, int out_size, void* d_ws, size_t ws_size,
                              hipStream_t stream)
{
    const float* logits = (const float*)d_in[0];
    const int*   labels = (const int*)d_in[1];
    const float* unc_th = (const float*)d_in[2];
    float*       out    = (float*)d_out;
    float4*      parts  = (float4*)d_ws;

    const int N = in_sizes[1];   // labels element count = rows
    const int BLOCKS = 2048;     // 8 blocks/CU, 8192 waves (32 waves/CU)
    const int TW = BLOCKS * (256 / 64);
    const int G  = (N + 7) >> 3;

    const bool exact = ((N & 7) == 0) && (G % TW == 0);
    if (exact) {
        avu_main<true><<<BLOCKS, 256, 0, stream>>>(logits, labels, unc_th, parts, N);
    } else {
        avu_main<false><<<BLOCKS, 256, 0, stream>>>(logits, labels, unc_th, parts, N);
    }
    avu_final<<<1, 64, 0, stream>>>(parts, BLOCKS, out);
}

// Round 4
// 371.955 us; speedup vs baseline: 1.0882x; 1.0882x over previous
//
#include <hip/hip_runtime.h>
#include <math.h>

// AvU loss over [N, 32] f32 logits.
// Per-wave LDS transpose: wave stages 64 rows (8 KiB) coalesced into its
// PRIVATE LDS region (no barriers; same-wave DS ops are ordered), each
// thread reads its own row back via rotated ds_read_b128 (2-way bank
// aliasing = free), then does the whole row's softmax stats with zero
// cross-lane ops. accurate = (x[label] == rowmax) — exact-tie probability
// is negligible vs the 1.26e-4 absmax threshold.

typedef float f32x4 __attribute__((ext_vector_type(4)));

__global__ __launch_bounds__(256) void avu_lds(
    const float* __restrict__ logits,
    const int* __restrict__ labels,
    const float* __restrict__ unc_th_p,
    float4* __restrict__ partials,    // [gridDim.x]
    int tilesPerWave)
{
    const float unc_th = unc_th_p[0];
    const f32x4* __restrict__ p4 = (const f32x4*)logits;

    __shared__ f32x4 lds4[2048];      // 4 waves x 512 f32x4 = 32 KiB

    const int lane = threadIdx.x & 63;
    const int wave = threadIdx.x >> 6;
    const int wavesPerBlock = blockDim.x >> 6;
    const int W = blockIdx.x * wavesPerBlock + wave;   // global wave id

    f32x4* __restrict__ wbuf = &lds4[wave << 9];       // wave-private 8 KiB

    float acc0 = 0.f, acc1 = 0.f, acc2 = 0.f, acc3 = 0.f;

    const int t0 = W * tilesPerWave;
    for (int i = 0; i < tilesPerWave; ++i) {
        const int tile = t0 + i;
        const size_t base4 = (size_t)tile << 9;        // tile * 512 f32x4

        const int lab = labels[(tile << 6) + lane];    // my row's label

        // stage 8 KiB: 8 coalesced 1 KiB loads -> wave-private LDS
        f32x4 tmp[8];
#pragma unroll
        for (int k = 0; k < 8; ++k)
            tmp[k] = p4[base4 + (k << 6) + lane];
#pragma unroll
        for (int k = 0; k < 8; ++k)
            wbuf[(k << 6) + lane] = tmp[k];

        // read my row (row = lane), rotated: slot s holds group g=(s+lane)&7
        f32x4 rv[8];
#pragma unroll
        for (int s = 0; s < 8; ++s) {
            const int g = (s + lane) & 7;
            rv[s] = wbuf[(lane << 3) + g];
        }

        // row max over 32 elems
        float pm[8];
#pragma unroll
        for (int s = 0; s < 8; ++s)
            pm[s] = fmaxf(fmaxf(rv[s].x, rv[s].y), fmaxf(rv[s].z, rv[s].w));
        const float m = fmaxf(fmaxf(fmaxf(pm[0], pm[1]), fmaxf(pm[2], pm[3])),
                              fmaxf(fmaxf(pm[4], pm[5]), fmaxf(pm[6], pm[7])));

        // x[label]: slot with group == (lab>>2) is s = ((lab>>2) - lane) & 7
        const int sl = ((lab >> 2) - lane) & 7;
        const int el = lab & 3;
        f32x4 vsel = rv[0];
#pragma unroll
        for (int s = 1; s < 8; ++s)
            if (sl == s) vsel = rv[s];
        const float c01  = (el & 1) ? vsel.y : vsel.x;
        const float c23  = (el & 1) ? vsel.w : vsel.z;
        const float x_lab = (el & 2) ? c23 : c01;

        // S = sum exp(x-m); dot = sum exp(x-m)*(x-m)
        float S = 0.f, dot = 0.f;
#pragma unroll
        for (int s = 0; s < 8; ++s) {
            const float d0 = rv[s].x - m, d1 = rv[s].y - m;
            const float d2 = rv[s].z - m, d3 = rv[s].w - m;
            const float e0 = __expf(d0), e1 = __expf(d1);
            const float e2 = __expf(d2), e3 = __expf(d3);
            S   += (e0 + e1) + (e2 + e3);
            dot += (e0 * d0 + e1 * d1) + (e2 * d2 + e3 * d3);
        }

        const float rS   = 1.0f / S;
        const float conf = rS;                    // max prob
        const float unc  = __logf(S) - dot * rS;  // entropy in [0, log 32]
        const float t    = 1.0f - 2.0f / (__expf(2.0f * unc) + 1.0f); // tanh

        const bool accurate = (x_lab == m);
        const bool certain  = (unc <= unc_th);

        const float a = accurate ? conf : (1.0f - conf);
        const float w = certain ? (1.0f - t) : t;
        const float val = a * w;

        acc0 += ( accurate &&  certain) ? val : 0.f;  // n_ac
        acc1 += ( accurate && !certain) ? val : 0.f;  // n_au
        acc2 += (!accurate &&  certain) ? val : 0.f;  // n_ic
        acc3 += (!accurate && !certain) ? val : 0.f;  // n_iu
    }

    // once-per-kernel wave butterfly + block reduce
#pragma unroll
    for (int mask = 1; mask <= 32; mask <<= 1) {
        acc0 += __shfl_xor(acc0, mask);
        acc1 += __shfl_xor(acc1, mask);
        acc2 += __shfl_xor(acc2, mask);
        acc3 += __shfl_xor(acc3, mask);
    }

    __shared__ float4 red[4];
    __syncthreads();   // all waves done with private LDS regions
    if (lane == 0) red[wave] = make_float4(acc0, acc1, acc2, acc3);
    __syncthreads();

    if (threadIdx.x == 0) {
        float4 r = red[0];
        for (int w2 = 1; w2 < wavesPerBlock; ++w2) {
            const float4 q = red[w2];
            r.x += q.x; r.y += q.y; r.z += q.z; r.w += q.w;
        }
        partials[blockIdx.x] = r;
    }
}

// Generic fallback (any N) — correctness only, never hit at N=2M.
__global__ __launch_bounds__(256) void avu_fallback(
    const float* __restrict__ logits,
    const int* __restrict__ labels,
    const float* __restrict__ unc_th_p,
    float4* __restrict__ partials,
    int N)
{
    const float unc_th = unc_th_p[0];
    float acc0 = 0.f, acc1 = 0.f, acc2 = 0.f, acc3 = 0.f;
    const int stride = gridDim.x * blockDim.x;
    for (int row = blockIdx.x * blockDim.x + threadIdx.x; row < N; row += stride) {
        const float* x = logits + (size_t)row * 32;
        float m = x[0]; int mi = 0;
        for (int c = 1; c < 32; ++c) { const float v = x[c]; if (v > m) { m = v; mi = c; } }
        float S = 0.f, dot = 0.f;
        for (int c = 0; c < 32; ++c) {
            const float d = x[c] - m; const float e = __expf(d);
            S += e; dot += e * d;
        }
        const float rS = 1.0f / S;
        const float unc = __logf(S) - dot * rS;
        const float t = 1.0f - 2.0f / (__expf(2.0f * unc) + 1.0f);
        const bool accurate = (labels[row] == mi);
        const bool certain = (unc <= unc_th);
        const float a = accurate ? rS : (1.0f - rS);
        const float w = certain ? (1.0f - t) : t;
        const float val = a * w;
        acc0 += ( accurate &&  certain) ? val : 0.f;
        acc1 += ( accurate && !certain) ? val : 0.f;
        acc2 += (!accurate &&  certain) ? val : 0.f;
        acc3 += (!accurate && !certain) ? val : 0.f;
    }
#pragma unroll
    for (int mask = 1; mask <= 32; mask <<= 1) {
        acc0 += __shfl_xor(acc0, mask);
        acc1 += __shfl_xor(acc1, mask);
        acc2 += __shfl_xor(acc2, mask);
        acc3 += __shfl_xor(acc3, mask);
    }
    __shared__ float4 red[4];
    const int wave = threadIdx.x >> 6;
    if ((threadIdx.x & 63) == 0) red[wave] = make_float4(acc0, acc1, acc2, acc3);
    __syncthreads();
    if (threadIdx.x == 0) {
        float4 r = red[0];
        for (int w2 = 1; w2 < (int)(blockDim.x >> 6); ++w2) {
            const float4 q = red[w2];
            r.x += q.x; r.y += q.y; r.z += q.z; r.w += q.w;
        }
        partials[blockIdx.x] = r;
    }
}

__global__ __launch_bounds__(64) void avu_final(
    const float4* __restrict__ partials, int nPart,
    float* __restrict__ out)
{
    double s0 = 0.0, s1 = 0.0, s2 = 0.0, s3 = 0.0;
    for (int i = threadIdx.x; i < nPart; i += 64) {
        const float4 p = partials[i];
        s0 += (double)p.x; s1 += (double)p.y;
        s2 += (double)p.z; s3 += (double)p.w;
    }
#pragma unroll
    for (int mask = 1; mask <= 32; mask <<= 1) {
        s0 += __shfl_xor(s0, mask);
        s1 += __shfl_xor(s1, mask);
        s2 += __shfl_xor(s2, mask);
        s3 += __shfl_xor(s3, mask);
    }
    if (threadIdx.x == 0) {
        const double avu = (s0 + s3) / (s0 + s1 + s2 + s3 + 1e-10);
        out[0] = (float)(-log(avu + 1e-10));
    }
}

extern "C" void kernel_launch(void* const* d_in, const int* in_sizes, int n_in,
                              void* d_out, int out_size, void* d_ws, size_t ws_size,
                              hipStream_t stream)
{
    const float* logits = (const float*)d_in[0];
    const int*   labels = (const int*)d_in[1];
    const float* unc_th = (const float*)d_in[2];
    float*       out    = (float*)d_out;
    float4*      parts  = (float4*)d_ws;

    const int N = in_sizes[1];          // rows
    const int BLOCKS = 1024;            // 4 blocks/CU (32 KiB LDS each)
    const int TW = BLOCKS * 4;          // 4096 waves

    const int tiles = N >> 6;           // 64-row tiles
    if ((N & 63) == 0 && tiles % TW == 0) {
        avu_lds<<<BLOCKS, 256, 0, stream>>>(logits, labels, unc_th, parts,
                                            tiles / TW);
    } else {
        avu_fallback<<<BLOCKS, 256, 0, stream>>>(logits, labels, unc_th, parts, N);
    }
    avu_final<<<1, 64, 0, stream>>>(parts, BLOCKS, out);
}

// Round 5
// 370.355 us; speedup vs baseline: 1.0929x; 1.0043x over previous
//
#include <hip/hip_runtime.h>
#include <math.h>

// AvU loss over [N, 32] f32 logits.
// Per-wave LDS transpose + cross-tile register prefetch:
//   - wave stages 64 rows (8 KiB) coalesced into its PRIVATE LDS region
//     (no barriers; same-wave DS ops are issue-ordered),
//   - next tile's 8 global loads are issued right after the current tile's
//     ds_writes, so their ~900-cyc latency hides under ds_read + compute,
//   - each thread reads its own row back via rotated ds_read_b128 (uniform
//     bank-quad spread = optimal for b128), then does the whole row's
//     softmax stats with zero cross-lane ops.
// accurate = (x[label] == rowmax); exact-tie probability is negligible vs
// the 1.26e-4 absmax threshold. All register arrays use compile-time
// constant indices (R3's dynamic-index spill trap avoided).

typedef float f32x4 __attribute__((ext_vector_type(4)));

__global__ __launch_bounds__(256) void avu_lds(
    const float* __restrict__ logits,
    const int* __restrict__ labels,
    const float* __restrict__ unc_th_p,
    float4* __restrict__ partials,    // [gridDim.x]
    int tilesPerWave)
{
    const float unc_th = unc_th_p[0];
    const f32x4* __restrict__ p4 = (const f32x4*)logits;

    __shared__ f32x4 lds4[2048];      // 4 waves x 512 f32x4 = 32 KiB

    const int lane = threadIdx.x & 63;
    const int wave = threadIdx.x >> 6;
    const int wavesPerBlock = blockDim.x >> 6;
    const int W = blockIdx.x * wavesPerBlock + wave;   // global wave id

    f32x4* __restrict__ wbuf = &lds4[wave << 9];       // wave-private 8 KiB

    float acc0 = 0.f, acc1 = 0.f, acc2 = 0.f, acc3 = 0.f;

    const int t0 = W * tilesPerWave;

    // prologue: load tile t0 into tmp
    f32x4 tmp[8];
    int lab = labels[(t0 << 6) + lane];
    {
        const size_t base4 = (size_t)t0 << 9;
#pragma unroll
        for (int k = 0; k < 8; ++k)
            tmp[k] = p4[base4 + (k << 6) + lane];
    }

    for (int i = 0; i < tilesPerWave; ++i) {
        // stage current tile into wave-private LDS (waits vmcnt per tmp[k])
#pragma unroll
        for (int k = 0; k < 8; ++k)
            wbuf[(k << 6) + lane] = tmp[k];

        const int clab = lab;

        // issue NEXT tile's loads now — latency hides under reads+compute
        f32x4 nxt[8];
        if (i + 1 < tilesPerWave) {
            const int tn = t0 + i + 1;
            const size_t base4 = (size_t)tn << 9;
#pragma unroll
            for (int k = 0; k < 8; ++k)
                nxt[k] = p4[base4 + (k << 6) + lane];
            lab = labels[(tn << 6) + lane];
        }

        // read my row (row = lane), rotated: slot s holds group g=(s+lane)&7
        f32x4 rv[8];
#pragma unroll
        for (int s = 0; s < 8; ++s) {
            const int g = (s + lane) & 7;
            rv[s] = wbuf[(lane << 3) + g];
        }

        // row max over 32 elems
        float pm[8];
#pragma unroll
        for (int s = 0; s < 8; ++s)
            pm[s] = fmaxf(fmaxf(rv[s].x, rv[s].y), fmaxf(rv[s].z, rv[s].w));
        const float m = fmaxf(fmaxf(fmaxf(pm[0], pm[1]), fmaxf(pm[2], pm[3])),
                              fmaxf(fmaxf(pm[4], pm[5]), fmaxf(pm[6], pm[7])));

        // x[label]: slot with group == (lab>>2) is s = ((lab>>2) - lane) & 7
        const int sl = ((clab >> 2) - lane) & 7;
        const int el = clab & 3;
        f32x4 vsel = rv[0];
#pragma unroll
        for (int s = 1; s < 8; ++s)
            if (sl == s) vsel = rv[s];
        const float c01   = (el & 1) ? vsel.y : vsel.x;
        const float c23   = (el & 1) ? vsel.w : vsel.z;
        const float x_lab = (el & 2) ? c23 : c01;

        // S = sum exp(x-m); dot = sum exp(x-m)*(x-m)
        float S = 0.f, dot = 0.f;
#pragma unroll
        for (int s = 0; s < 8; ++s) {
            const float d0 = rv[s].x - m, d1 = rv[s].y - m;
            const float d2 = rv[s].z - m, d3 = rv[s].w - m;
            const float e0 = __expf(d0), e1 = __expf(d1);
            const float e2 = __expf(d2), e3 = __expf(d3);
            S   += (e0 + e1) + (e2 + e3);
            dot += (e0 * d0 + e1 * d1) + (e2 * d2 + e3 * d3);
        }

        const float rS   = 1.0f / S;
        const float conf = rS;                    // max prob
        const float unc  = __logf(S) - dot * rS;  // entropy in [0, log 32]
        const float t    = 1.0f - 2.0f / (__expf(2.0f * unc) + 1.0f); // tanh

        const bool accurate = (x_lab == m);
        const bool certain  = (unc <= unc_th);

        const float a = accurate ? conf : (1.0f - conf);
        const float w = certain ? (1.0f - t) : t;
        const float val = a * w;

        acc0 += ( accurate &&  certain) ? val : 0.f;  // n_ac
        acc1 += ( accurate && !certain) ? val : 0.f;  // n_au
        acc2 += (!accurate &&  certain) ? val : 0.f;  // n_ic
        acc3 += (!accurate && !certain) ? val : 0.f;  // n_iu

        // rotate prefetch registers (constant indices — stays in VGPRs)
#pragma unroll
        for (int k = 0; k < 8; ++k)
            tmp[k] = nxt[k];
    }

    // once-per-kernel wave butterfly + block reduce
#pragma unroll
    for (int mask = 1; mask <= 32; mask <<= 1) {
        acc0 += __shfl_xor(acc0, mask);
        acc1 += __shfl_xor(acc1, mask);
        acc2 += __shfl_xor(acc2, mask);
        acc3 += __shfl_xor(acc3, mask);
    }

    __shared__ float4 red[4];
    if (lane == 0) red[wave] = make_float4(acc0, acc1, acc2, acc3);
    __syncthreads();

    if (threadIdx.x == 0) {
        float4 r = red[0];
        for (int w2 = 1; w2 < wavesPerBlock; ++w2) {
            const float4 q = red[w2];
            r.x += q.x; r.y += q.y; r.z += q.z; r.w += q.w;
        }
        partials[blockIdx.x] = r;
    }
}

// Generic fallback (any N) — correctness only, never hit at N=2M.
__global__ __launch_bounds__(256) void avu_fallback(
    const float* __restrict__ logits,
    const int* __restrict__ labels,
    const float* __restrict__ unc_th_p,
    float4* __restrict__ partials,
    int N)
{
    const float unc_th = unc_th_p[0];
    float acc0 = 0.f, acc1 = 0.f, acc2 = 0.f, acc3 = 0.f;
    const int stride = gridDim.x * blockDim.x;
    for (int row = blockIdx.x * blockDim.x + threadIdx.x; row < N; row += stride) {
        const float* x = logits + (size_t)row * 32;
        float m = x[0]; int mi = 0;
        for (int c = 1; c < 32; ++c) { const float v = x[c]; if (v > m) { m = v; mi = c; } }
        float S = 0.f, dot = 0.f;
        for (int c = 0; c < 32; ++c) {
            const float d = x[c] - m; const float e = __expf(d);
            S += e; dot += e * d;
        }
        const float rS = 1.0f / S;
        const float unc = __logf(S) - dot * rS;
        const float t = 1.0f - 2.0f / (__expf(2.0f * unc) + 1.0f);
        const bool accurate = (labels[row] == mi);
        const bool certain = (unc <= unc_th);
        const float a = accurate ? rS : (1.0f - rS);
        const float w = certain ? (1.0f - t) : t;
        const float val = a * w;
        acc0 += ( accurate &&  certain) ? val : 0.f;
        acc1 += ( accurate && !certain) ? val : 0.f;
        acc2 += (!accurate &&  certain) ? val : 0.f;
        acc3 += (!accurate && !certain) ? val : 0.f;
    }
#pragma unroll
    for (int mask = 1; mask <= 32; mask <<= 1) {
        acc0 += __shfl_xor(acc0, mask);
        acc1 += __shfl_xor(acc1, mask);
        acc2 += __shfl_xor(acc2, mask);
        acc3 += __shfl_xor(acc3, mask);
    }
    __shared__ float4 red[4];
    const int wave = threadIdx.x >> 6;
    if ((threadIdx.x & 63) == 0) red[wave] = make_float4(acc0, acc1, acc2, acc3);
    __syncthreads();
    if (threadIdx.x == 0) {
        float4 r = red[0];
        for (int w2 = 1; w2 < (int)(blockDim.x >> 6); ++w2) {
            const float4 q = red[w2];
            r.x += q.x; r.y += q.y; r.z += q.z; r.w += q.w;
        }
        partials[blockIdx.x] = r;
    }
}

__global__ __launch_bounds__(64) void avu_final(
    const float4* __restrict__ partials, int nPart,
    float* __restrict__ out)
{
    double s0 = 0.0, s1 = 0.0, s2 = 0.0, s3 = 0.0;
    for (int i = threadIdx.x; i < nPart; i += 64) {
        const float4 p = partials[i];
        s0 += (double)p.x; s1 += (double)p.y;
        s2 += (double)p.z; s3 += (double)p.w;
    }
#pragma unroll
    for (int mask = 1; mask <= 32; mask <<= 1) {
        s0 += __shfl_xor(s0, mask);
        s1 += __shfl_xor(s1, mask);
        s2 += __shfl_xor(s2, mask);
        s3 += __shfl_xor(s3, mask);
    }
    if (threadIdx.x == 0) {
        const double avu = (s0 + s3) / (s0 + s1 + s2 + s3 + 1e-10);
        out[0] = (float)(-log(avu + 1e-10));
    }
}

extern "C" void kernel_launch(void* const* d_in, const int* in_sizes, int n_in,
                              void* d_out, int out_size, void* d_ws, size_t ws_size,
                              hipStream_t stream)
{
    const float* logits = (const float*)d_in[0];
    const int*   labels = (const int*)d_in[1];
    const float* unc_th = (const float*)d_in[2];
    float*       out    = (float*)d_out;
    float4*      parts  = (float4*)d_ws;

    const int N = in_sizes[1];          // rows
    const int BLOCKS = 1024;            // 32 KiB LDS each; ~3 blocks/CU at ~130 VGPR
    const int TW = BLOCKS * 4;          // 4096 waves

    const int tiles = N >> 6;           // 64-row tiles
    if ((N & 63) == 0 && tiles % TW == 0) {
        avu_lds<<<BLOCKS, 256, 0, stream>>>(logits, labels, unc_th, parts,
                                            tiles / TW);
    } else {
        avu_fallback<<<BLOCKS, 256, 0, stream>>>(logits, labels, unc_th, parts, N);
    }
    avu_final<<<1, 64, 0, stream>>>(parts, BLOCKS, out);
}